// Round 12
// baseline (198.852 us; speedup 1.0000x reference)
//
#include <hip/hip_runtime.h>

typedef __attribute__((ext_vector_type(8))) short bf16x8;
typedef __attribute__((ext_vector_type(4))) float f32x4;

#define NT 26
#define BROWS 16
#define TILES 16
#define NKS 19               // k-steps of 32; K = 608 (584 real + 24 zero)
#define ABUF_B (14 * 16 * 128)   // 28,672 B per class-A fp32 buffer
#define MSTR 336             // mini row stride bytes
#define Z1STR 68             // fp32 z1 row stride (dwords)
#define WS_FRAG_DWORDS 19456 // 19 ks * 4 n * 64 lanes * 8 bf16 / 2

__constant__ int c_OFFS[NT] = {
    0,1000001,1500002,1600003,1650004,1660005,1670006,1675007,1680008,1681009,
    1682010,1682511,1683012,1683113,1683214,1683265,1683316,1683337,1683358,
    1683369,1683380,1683386,1683392,1683396,1683400,1683403};

// prep tables: padded col starts (cat-relative), true dims, true concat offs
// padded widths: t0-13: 32 | t14-17: 16 | t18-19: 8 | t20-25: 4  (sum 552; K=608)
__constant__ int c_P_COLP[NT] = {
    0,32,64,96,128,160,192,224,256,288,320,352,384,416,448,464,480,496,
    512,520,528,532,536,540,544,548};
__constant__ int c_P_DIMS[NT] = {
    32,32,32,32,32,32,32,32,32,32,32,32,21,21,14,14,9,9,6,6,4,4,4,4,4,4};
__constant__ int c_P_COLF[NT] = {
    0,32,64,96,128,160,192,224,256,288,320,352,384,405,426,440,454,463,
    472,478,484,488,492,496,500,504};

__device__ __forceinline__ unsigned short f2bf(float f) {
  unsigned int u = __builtin_bit_cast(unsigned int, f);
  u += 0x7fffu + ((u >> 16) & 1u);       // RNE
  return (unsigned short)(u >> 16);
}

__device__ __forceinline__ unsigned cvtpk(float a, float b) {
  unsigned r;                             // lo = a, hi = b (RNE)
  asm("v_cvt_pk_bf16_f32 %0, %1, %2" : "=v"(r) : "v"(a), "v"(b));
  return r;
}

__device__ __forceinline__ uint2 pk2(float4 a) {
  uint2 o;
  o.x = cvtpk(a.x, a.y); o.y = cvtpk(a.z, a.w);
  return o;
}

__device__ __forceinline__ bf16x8 pk8(f32x4 lo, f32x4 hi) {
  uint4 u;
  u.x = cvtpk(lo[0], lo[1]); u.y = cvtpk(lo[2], lo[3]);
  u.z = cvtpk(hi[0], hi[1]); u.w = cvtpk(hi[2], hi[3]);
  return __builtin_bit_cast(bf16x8, u);
}

__device__ __forceinline__ float silu_f(float x) {
  return x / (1.0f + __expf(-x));
}

// ---- prep: W1 (fp32 [540][64]) -> bf16 MFMA B-fragments (padded-608 layout) --
extern "C" __global__ void __launch_bounds__(256)
prep_w1(const float* __restrict__ W1, unsigned int* __restrict__ wsf) {
  const int g = blockIdx.x * 256 + threadIdx.x;   // output dword index
  if (g >= WS_FRAG_DWORDS) return;
  const int f  = g * 2;
  const int j  = f & 7;
  const int l  = (f >> 3) & 63;
  const int w  = (f >> 9) & 3;
  const int ks = f >> 11;
  const int bn = (w << 4) + (l & 15);
  const int k0 = (ks << 5) + ((l >> 4) << 3) + j;
  float v[2];
  #pragma unroll
  for (int e = 0; e < 2; ++e) {
    const int k = k0 + e;
    float x = 0.0f;
    if (k < 32) {
      x = W1[k * 64 + bn];                 // h block: W1 rows 0..31
    } else {
      const int c = k - 32;                // padded cat col (0..575)
      for (int i = 0; i < NT; ++i) {
        const int off = c - c_P_COLP[i];
        if (off >= 0 && off < c_P_DIMS[i])
          x = W1[(32 + c_P_COLF[i] + off) * 64 + bn];
      }                                    // pad cols & c>=552 stay 0
    }
    v[e] = x;
  }
  wsf[g] = ((unsigned)f2bf(v[0])) | (((unsigned)f2bf(v[1])) << 16);
}

extern "C" __global__ void __launch_bounds__(256, 2)
tab_fused(const float* __restrict__ xc,   // [B,64]
          const int* __restrict__ xcat,   // [B,26]
          const float* __restrict__ emb,  // [TOTAL_ROWS,32]
          const float* __restrict__ Wc,   // [64,32]
          const float* __restrict__ bc,   // [32]
          const float* __restrict__ lng,  // [32]
          const float* __restrict__ lnb,  // [32]
          const unsigned short* __restrict__ wsf,  // W1 bf16 fragments
          const float* __restrict__ b1,   // [64]
          const float* __restrict__ W2,   // [64,32]
          const float* __restrict__ b2,   // [32]
          float* __restrict__ out) {      // [B,32]
  // Abuf: fp32 class-A staging, [buf][table u][row][slot], slot = chunk^(row&7),
  //       filled by global_load_lds (linear dest, pre-swizzled per-lane source).
  // mini: bf16 per-row [336 B]: ks15 B[0,128) | ks17 C[128,160) D[160,208)
  //       zeros[208,256) | ks0 h[256,320) | slack. z1/xs separate (no aliasing).
  __shared__ __attribute__((aligned(16))) char Abuf[2][ABUF_B];   // 57,344 B
  __shared__ __attribute__((aligned(16))) char mini[BROWS * MSTR]; //  5,376 B
  __shared__ __attribute__((aligned(16))) float z1[BROWS * Z1STR]; //  4,352 B
  __shared__ __attribute__((aligned(16))) int xs[BROWS * NT];      //  1,664 B

  const int t  = threadIdx.x;
  const int w  = t >> 6;          // wave id: owns output n-slice w
  const int l  = t & 63;          // lane
  const int T0R = blockIdx.x * (TILES * BROWS);   // first batch row

  const int bn = (w << 4) + (l & 15);   // output column owned by this lane

  // lane roles (tile-invariant; BCD/h/phase3 are R10's verified 16-row maps)
  const int rB16 = t >> 4, tB = (t >> 2) & 3, qB = t & 3;      // class B
  const int rowC = t >> 2, tabC = 18 + ((t >> 1) & 1), qC = t & 1;
  const int rowD = t >> 3, slotD = t & 7;
  const bool hasC = (t < 64);
  const bool hasD = (t < 128) && (slotD < 6);
  const int rH = t >> 4, jH = (t & 15) << 1;                   // cont-MLP/ph3
  const float b1v = b1[bn];

  // class-A gld: wave w issues 7 instrs: g = w&1, u = i*2 + (w>>1)
  const int gA  = w & 1;
  const int uA0 = w >> 1;
  const int rlA = (gA << 3) + (l >> 3);          // source row for this lane
  const int csw = (l & 7) ^ (l >> 3);            // pre-swizzled source chunk

  // MFMA read-side constants
  const int rl  = l & 15;
  const int kg16 = (l >> 4) << 4;                 // 16B group in bf16 rows
  const int c0  = (l >> 4) << 1;
  const int sA0 = ((c0)     ^ (rl & 7)) << 4;     // swizzled fp32 chunk bytes
  const int sA1 = ((c0 + 1) ^ (rl & 7)) << 4;

#define GLDA_ISSUE(BUF, R0)                                                    \
  {                                                                            \
    _Pragma("unroll")                                                          \
    for (int i = 0; i < 7; ++i) {                                              \
      const int u = i * 2 + uA0;                                               \
      const int idx = xs[rlA * NT + u];                                        \
      const float* src = emb + ((size_t)(c_OFFS[u] + idx) << 5) + (csw << 2);  \
      __builtin_amdgcn_global_load_lds(                                        \
          (const __attribute__((address_space(1))) void*)src,                  \
          (__attribute__((address_space(3))) void*)(Abuf[BUF] +                \
              (u * 16 + gA * 8) * 128),                                        \
          16, 0, 0);                                                           \
    }                                                                          \
  }

#define BCD_LOAD()                                                             \
  {                                                                            \
    const int idxB = xs[rB16 * NT + 14 + tB];                                  \
    vB = *(const float4*)(emb + ((size_t)(c_OFFS[14 + tB] + idxB) << 5) + (qB << 2)); \
    if (hasC) {                                                                \
      const int idxC = xs[rowC * NT + tabC];                                   \
      vC = *(const float4*)(emb + ((size_t)(c_OFFS[tabC] + idxC) << 5) + (qC << 2)); \
    }                                                                          \
    if (hasD) {                                                                \
      const int idxD = xs[rowD * NT + 20 + slotD];                             \
      vD = *(const float4*)(emb + ((size_t)(c_OFFS[20 + slotD] + idxD) << 5)); \
    }                                                                          \
  }

  // ---------------- prologue ---------------------------------------------------
  float4 vB, vC = {0.f,0.f,0.f,0.f}, vD = {0.f,0.f,0.f,0.f};
  int4 xv = {0, 0, 0, 0};
  if (t < 48) {                          // zeros (k 584..607) — persist all tiles
    uint4 zz = {0u, 0u, 0u, 0u};
    *(uint4*)(mini + (t / 3) * MSTR + 208 + (t % 3) * 16) = zz;
  }
  if (t < 104) ((int4*)xs)[t] = ((const int4*)(xcat + (size_t)T0R * NT))[t];
  __syncthreads();
  BCD_LOAD();                            // tile 0 BCD -> regs
  if (t < 104) xv = ((const int4*)(xcat + (size_t)(T0R + BROWS) * NT))[t];
  GLDA_ISSUE(0, T0R);                    // tile 0 class-A in flight
  asm volatile("s_waitcnt lgkmcnt(0)" ::: "memory");   // xs reads retired
  __builtin_amdgcn_s_barrier();          // raw: vmcnt NOT drained
  __builtin_amdgcn_sched_barrier(0);

  #pragma unroll 1
  for (int n = 0; n < TILES; ++n) {
    const int R0 = T0R + n * BROWS;

    // ---- step1: cont-MLP h(n) (R10 verbatim) ---------------------------------
    unsigned hwp;
    {
      const float* xr = xc + (size_t)(R0 + rH) * 64;
      float h0 = bc[jH], h1 = bc[jH + 1];
      #pragma unroll 4
      for (int k4 = 0; k4 < 16; ++k4) {
        const float4 x4 = ((const float4*)xr)[k4];
        #pragma unroll
        for (int kk = 0; kk < 4; ++kk) {
          const float xk = (kk == 0) ? x4.x : (kk == 1) ? x4.y : (kk == 2) ? x4.z : x4.w;
          const float2 wv = *(const float2*)(Wc + (k4 * 4 + kk) * 32 + jH);
          h0 = __fmaf_rn(xk, wv.x, h0);
          h1 = __fmaf_rn(xk, wv.y, h1);
        }
      }
      float s1 = h0 + h1;
      float s2 = h0 * h0 + h1 * h1;
      #pragma unroll
      for (int m = 1; m < 16; m <<= 1) {
        s1 += __shfl_xor(s1, m);
        s2 += __shfl_xor(s2, m);
      }
      const float mu = s1 * 0.03125f;
      const float var = s2 * 0.03125f - mu * mu;
      const float rs = rsqrtf(var + 1e-5f);
      const float g0 = silu_f((h0 - mu) * rs * lng[jH]     + lnb[jH]);
      const float g1 = silu_f((h1 - mu) * rs * lng[jH + 1] + lnb[jH + 1]);
      hwp = cvtpk(g0, g1);
    }

    // ---- step2: write mini(n) + xs(n+1) --------------------------------------
    *(unsigned*)(mini + rH * MSTR + 256 + jH * 2) = hwp;
    *(uint2*)(mini + rB16 * MSTR + tB * 32 + qB * 8) = pk2(vB);
    if (hasC)
      *(uint2*)(mini + rowC * MSTR + 128 + (tabC - 18) * 16 + qC * 8) = pk2(vC);
    if (hasD)
      *(uint2*)(mini + rowD * MSTR + 160 + slotD * 8) = pk2(vD);
    if (n + 1 < TILES && t < 104) ((int4*)xs)[t] = xv;
    __syncthreads();   // step3: drains vmcnt -> Abuf[n&1] complete + LDS visible

    // ---- step4: prefetch tile n+1 (BCD regs first, then zero-reg gldA) -------
    if (n + 1 < TILES) {
      BCD_LOAD();                          // waits later at vmcnt(>=7): gldA flows
      if (n + 2 < TILES && t < 104)
        xv = ((const int4*)(xcat + (size_t)(T0R + (n + 2) * BROWS) * NT))[t];
      GLDA_ISSUE((n + 1) & 1, R0 + BROWS);
      __builtin_amdgcn_sched_barrier(0);   // pin issue before MFMA
    }

    // ---- step5: MFMA over K=608 ----------------------------------------------
    f32x4 acc = {0.f, 0.f, 0.f, 0.f};
    {
      bf16x8 bwbuf[4];
      #pragma unroll
      for (int p = 0; p < 4; ++p)
        bwbuf[p] = *(const bf16x8*)(wsf + ((p * 4 + w) * 64 + l) * 8);
      const char* abase = Abuf[n & 1] + rl * 128;
      const char* mrow  = mini + rl * MSTR;
      #pragma unroll
      for (int ks = 0; ks < NKS; ++ks) {
        const bf16x8 bw = bwbuf[ks & 3];
        if (ks + 4 < NKS)
          bwbuf[ks & 3] = *(const bf16x8*)(wsf + (((ks + 4) * 4 + w) * 64 + l) * 8);
        bf16x8 a;
        if (ks == 0) {
          a = *(const bf16x8*)(mrow + 256 + kg16);
        } else if (ks <= 14) {
          const char* ab = abase + (ks - 1) * (16 * 128);
          a = pk8(*(const f32x4*)(ab + sA0), *(const f32x4*)(ab + sA1));
        } else {
          a = *(const bf16x8*)(mrow + (ks - 15) * 64 + kg16);
        }
        acc = __builtin_amdgcn_mfma_f32_16x16x32_bf16(a, bw, acc, 0, 0, 0);
      }
    }

    // ---- step6: z1 = silu(acc + b1) ------------------------------------------
    {
      const int rb2 = (l >> 4) << 2;
      #pragma unroll
      for (int v = 0; v < 4; ++v)
        z1[(rb2 + v) * Z1STR + bn] = silu_f(acc[v] + b1v);  // row=(l>>4)*4+v
    }
    // step7: raw barrier, lgkm only — tile n+1's gathers stay in flight
    asm volatile("s_waitcnt lgkmcnt(0)" ::: "memory");
    __builtin_amdgcn_s_barrier();

    // ---- step8: out = silu(z1 @ W2 + b2) (R10 verbatim) ----------------------
    {
      float a0 = b2[jH], a1 = b2[jH + 1];
      const float4* zr4 = (const float4*)&z1[rH * Z1STR];
      #pragma unroll 4
      for (int k4 = 0; k4 < 16; ++k4) {
        const float4 zv = zr4[k4];
        #pragma unroll
        for (int kk = 0; kk < 4; ++kk) {
          const float zk = (kk == 0) ? zv.x : (kk == 1) ? zv.y : (kk == 2) ? zv.z : zv.w;
          const float2 wv = *(const float2*)(W2 + (k4 * 4 + kk) * 32 + jH);
          a0 = __fmaf_rn(zk, wv.x, a0);
          a1 = __fmaf_rn(zk, wv.y, a1);
        }
      }
      float2 o;
      o.x = silu_f(a0);
      o.y = silu_f(a1);
      *(float2*)(out + (size_t)(R0 + rH) * 32 + jH) = o;
    }
  }
}

extern "C" void kernel_launch(void* const* d_in, const int* in_sizes, int n_in,
                              void* d_out, int out_size, void* d_ws, size_t ws_size,
                              hipStream_t stream) {
  const float* xc   = (const float*)d_in[0];
  const int*   xcat = (const int*)  d_in[1];
  const float* emb  = (const float*)d_in[2];
  const float* Wc   = (const float*)d_in[3];
  const float* bc   = (const float*)d_in[4];
  const float* lng  = (const float*)d_in[5];
  const float* lnb  = (const float*)d_in[6];
  const float* W1   = (const float*)d_in[7];
  const float* b1   = (const float*)d_in[8];
  const float* W2   = (const float*)d_in[9];
  const float* b2   = (const float*)d_in[10];
  float* out = (float*)d_out;

  unsigned int* wsf = (unsigned int*)d_ws;     // 77,824 B of W1 fragments
  hipLaunchKernelGGL(prep_w1, dim3((WS_FRAG_DWORDS + 255) / 256), dim3(256),
                     0, stream, W1, wsf);

  const int B = in_sizes[0] / 64;          // 131072
  const int grid = B / (BROWS * TILES);    // 512
  hipLaunchKernelGGL(tab_fused, dim3(grid), dim3(256), 0, stream,
                     xc, xcat, emb, Wc, bc, lng, lnb,
                     (const unsigned short*)wsf, b1, W2, b2, out);
}

// Round 13
// 112.849 us; speedup vs baseline: 1.7621x; 1.7621x over previous
//
#include <hip/hip_runtime.h>

typedef __attribute__((ext_vector_type(8))) short bf16x8;
typedef __attribute__((ext_vector_type(4))) float f32x4;

#define NT 26
#define BROWS 32
#define NKS 19             // k-steps of 32; K total = 608 (584 real + 24 zero)
#define LDSTR 616          // bf16 elems per tile row; 1232 B stride
#define Z1STR 68           // fp32 z1 row stride (dwords)
#define WS_FRAG_DWORDS 19456   // 19 ks * 4 n * 64 lanes * 8 bf16 / 2

__constant__ int c_OFFS[NT] = {
    0,1000001,1500002,1600003,1650004,1660005,1670006,1675007,1680008,1681009,
    1682010,1682511,1683012,1683113,1683214,1683265,1683316,1683337,1683358,
    1683369,1683380,1683386,1683392,1683396,1683400,1683403};

// prep tables: padded col starts (cat-relative), true dims, true concat offs
// padded widths: t0-13: 32 | t14-17: 16 | t18-19: 8 | t20-25: 4  (sum 552; K=608)
__constant__ int c_P_COLP[NT] = {
    0,32,64,96,128,160,192,224,256,288,320,352,384,416,448,464,480,496,
    512,520,528,532,536,540,544,548};
__constant__ int c_P_DIMS[NT] = {
    32,32,32,32,32,32,32,32,32,32,32,32,21,21,14,14,9,9,6,6,4,4,4,4,4,4};
__constant__ int c_P_COLF[NT] = {
    0,32,64,96,128,160,192,224,256,288,320,352,384,405,426,440,454,463,
    472,478,484,488,492,496,500,504};

__device__ __forceinline__ unsigned short f2bf(float f) {
  unsigned int u = __builtin_bit_cast(unsigned int, f);
  u += 0x7fffu + ((u >> 16) & 1u);       // RNE
  return (unsigned short)(u >> 16);
}

__device__ __forceinline__ unsigned cvtpk(float a, float b) {
  unsigned r;                             // lo = a, hi = b (RNE)
  asm("v_cvt_pk_bf16_f32 %0, %1, %2" : "=v"(r) : "v"(a), "v"(b));
  return r;
}

__device__ __forceinline__ uint2 pk2(float4 a) {
  uint2 o;
  o.x = cvtpk(a.x, a.y); o.y = cvtpk(a.z, a.w);
  return o;
}

__device__ __forceinline__ float silu_f(float x) {
  return x / (1.0f + __expf(-x));
}

// ---- prep: W1 (fp32 [540][64]) -> bf16 MFMA B-fragments (padded-608 layout) --
// frag bf16 index f = ((ks*4 + n)*64 + l)*8 + j ; k = ks*32+(l>>4)*8+j ; col n*16+(l&15)
extern "C" __global__ void __launch_bounds__(256)
prep_w1(const float* __restrict__ W1, unsigned int* __restrict__ wsf) {
  const int g = blockIdx.x * 256 + threadIdx.x;   // output dword index
  if (g >= WS_FRAG_DWORDS) return;
  const int f  = g * 2;
  const int j  = f & 7;
  const int l  = (f >> 3) & 63;
  const int w  = (f >> 9) & 3;
  const int ks = f >> 11;
  const int bn = (w << 4) + (l & 15);
  const int k0 = (ks << 5) + ((l >> 4) << 3) + j;
  float v[2];
  #pragma unroll
  for (int e = 0; e < 2; ++e) {
    const int k = k0 + e;
    float x = 0.0f;
    if (k < 32) {
      x = W1[k * 64 + bn];                 // h block: W1 rows 0..31
    } else {
      const int c = k - 32;                // padded cat col (0..575)
      for (int i = 0; i < NT; ++i) {
        const int off = c - c_P_COLP[i];
        if (off >= 0 && off < c_P_DIMS[i])
          x = W1[(32 + c_P_COLF[i] + off) * 64 + bn];
      }                                    // pad cols & c>=552 stay 0
    }
    v[e] = x;
  }
  wsf[g] = ((unsigned)f2bf(v[0])) | (((unsigned)f2bf(v[1])) << 16);
}

extern "C" __global__ void __launch_bounds__(256, 2)
tab_fused(const float* __restrict__ xc,   // [B,64]
          const int* __restrict__ xcat,   // [B,26]
          const float* __restrict__ emb,  // [TOTAL_ROWS,32]
          const float* __restrict__ Wc,   // [64,32]
          const float* __restrict__ bc,   // [32]
          const float* __restrict__ lng,  // [32]
          const float* __restrict__ lnb,  // [32]
          const unsigned short* __restrict__ wsf,  // W1 bf16 fragments
          const float* __restrict__ b1,   // [64]
          const float* __restrict__ W2,   // [64,32]
          const float* __restrict__ b2,   // [32]
          float* __restrict__ out) {      // [B,32]
  // bf16 tile [32][LDSTR] during phases 1-2; z1 (fp32 [32][Z1STR]) aliases after.
  // Row byte map: h[0,64) A[64,960) B[960,1088) C[1088,1120) D[1120,1168)
  //               zeros[1168,1216) slack[1216,1232)
  __shared__ __attribute__((aligned(16))) float smem[(BROWS * LDSTR) / 2]; // 39,424 B
  unsigned short* fused = (unsigned short*)smem;
  char* tbb = (char*)smem;
  float* z1 = smem;

  const int t  = threadIdx.x;
  const int w  = t >> 6;          // wave id: owns output n-slice w
  const int l  = t & 63;          // lane
  const int R0 = blockIdx.x * BROWS;

  const int bn = (w << 4) + (l & 15);   // output column owned by this lane
  const int kg = (l >> 4) << 3;         // k sub-offset within a k-step

  // zero tile cols 584..607 (48 B per row); visible by the pre-MFMA barrier
  if (t >= 160) {
    const int tt = t - 160;
    uint4 zz = {0u, 0u, 0u, 0u};
    *(uint4*)(tbb + (tt / 3) * (LDSTR * 2) + 1168 + (tt % 3) * 16) = zz;
  }

  // ---------------- phase 1a: lane-cooperative gather (coalesced) -------------
  // Class A (tables 0..13, 8 quads/row): 8 lanes load one row's 128 B contig.
  // Indices straight from xcat: 7 aligned int2 loads = tables 0..13.
  const int rowA = (w << 3) + (l >> 3);   // this lane's row for ALL class-A insts
  const int qA = l & 7;
  const int2* xrA = (const int2*)(xcat + (size_t)(R0 + rowA) * NT);  // 8B-aligned
  int2 xi[7];
  #pragma unroll
  for (int u = 0; u < 7; ++u) xi[u] = xrA[u];
  float4 vA[14];
  #pragma unroll
  for (int u = 0; u < 14; ++u) {
    const int idx = (u & 1) ? xi[u >> 1].y : xi[u >> 1].x;
    vA[u] = *(const float4*)(emb + ((size_t)(c_OFFS[u] + idx) << 5) + (qA << 2));
  }
  // Class B (tables 14..17, 4 quads): 4 lanes per row.
  const int pbb = (w << 4) + (l >> 2);    // 0..63
  const int rowB = pbb & 31;
  const int qB = l & 3;
  float4 vB[2];
  #pragma unroll
  for (int u = 0; u < 2; ++u) {
    const int tab = 14 + (u << 1) + (pbb >> 5);
    const int idx = xcat[(size_t)(R0 + rowB) * NT + tab];
    vB[u] = *(const float4*)(emb + ((size_t)(c_OFFS[tab] + idx) << 5) + (qB << 2));
  }
  // Class C (tables 18,19, 2 quads): 2 lanes per row; waves 0,1 only.
  const bool hasC = (w < 2);
  const int rowC = l >> 1, tabC = 18 + w, qC = l & 1;
  float4 vC = {0.f, 0.f, 0.f, 0.f};
  if (hasC) {
    const int idx = xcat[(size_t)(R0 + rowC) * NT + tabC];
    vC = *(const float4*)(emb + ((size_t)(c_OFFS[tabC] + idx) << 5) + (qC << 2));
  }
  // Class D (tables 20..25, 1 quad): 1 lane per row; waves 0,2,3.
  const bool hasD = (w != 1);
  const int dD = (w == 2) ? 0 : ((w == 3) ? 1 : 2);
  const int tabD = 20 + (dD << 1) + (l >> 5);
  const int rowD = l & 31;
  float4 vD = {0.f, 0.f, 0.f, 0.f};
  if (hasD) {
    const int idx = xcat[(size_t)(R0 + rowD) * NT + tabD];
    vD = *(const float4*)(emb + ((size_t)(c_OFFS[tabD] + idx) << 5));
  }

  // ---------------- phase 1b: cont MLP -> bf16 into tile cols 0..31 -----------
  {
    const int r  = t >> 3;
    const int j0 = (t & 7) << 2;
    const float* xr = xc + (size_t)(R0 + r) * 64;
    float h0 = bc[j0], h1 = bc[j0 + 1], h2 = bc[j0 + 2], h3 = bc[j0 + 3];
    #pragma unroll 4
    for (int k4 = 0; k4 < 16; ++k4) {
      const float4 x4 = ((const float4*)xr)[k4];
      const float* wb = Wc + (k4 * 4) * 32 + j0;
      const float4 w0 = *(const float4*)(wb);
      const float4 w1 = *(const float4*)(wb + 32);
      const float4 w2 = *(const float4*)(wb + 64);
      const float4 w3 = *(const float4*)(wb + 96);
      h0 = __fmaf_rn(x4.x, w0.x, h0); h1 = __fmaf_rn(x4.x, w0.y, h1);
      h2 = __fmaf_rn(x4.x, w0.z, h2); h3 = __fmaf_rn(x4.x, w0.w, h3);
      h0 = __fmaf_rn(x4.y, w1.x, h0); h1 = __fmaf_rn(x4.y, w1.y, h1);
      h2 = __fmaf_rn(x4.y, w1.z, h2); h3 = __fmaf_rn(x4.y, w1.w, h3);
      h0 = __fmaf_rn(x4.z, w2.x, h0); h1 = __fmaf_rn(x4.z, w2.y, h1);
      h2 = __fmaf_rn(x4.z, w2.z, h2); h3 = __fmaf_rn(x4.z, w2.w, h3);
      h0 = __fmaf_rn(x4.w, w3.x, h0); h1 = __fmaf_rn(x4.w, w3.y, h1);
      h2 = __fmaf_rn(x4.w, w3.z, h2); h3 = __fmaf_rn(x4.w, w3.w, h3);
    }
    float s1v = h0 + h1 + h2 + h3;
    float s2v = h0 * h0 + h1 * h1 + h2 * h2 + h3 * h3;
    #pragma unroll
    for (int m = 1; m < 8; m <<= 1) {
      s1v += __shfl_xor(s1v, m);
      s2v += __shfl_xor(s2v, m);
    }
    const float mu = s1v * 0.03125f;
    const float var = s2v * 0.03125f - mu * mu;
    const float rs = rsqrtf(var + 1e-5f);
    const float g0 = silu_f((h0 - mu) * rs * lng[j0]     + lnb[j0]);
    const float g1 = silu_f((h1 - mu) * rs * lng[j0 + 1] + lnb[j0 + 1]);
    const float g2 = silu_f((h2 - mu) * rs * lng[j0 + 2] + lnb[j0 + 2]);
    const float g3 = silu_f((h3 - mu) * rs * lng[j0 + 3] + lnb[j0 + 3]);
    uint2 hw;
    hw.x = cvtpk(g0, g1);
    hw.y = cvtpk(g2, g3);
    *(uint2*)(tbb + r * (LDSTR * 2) + j0 * 2) = hw;
  }

  // ---------------- phase 1c: convert + write gathered quads ------------------
  {
    // A: col = 32 + u*32 + qA*4  -> byte = 64 + u*64 + qA*8
    char* dA = tbb + rowA * (LDSTR * 2) + 64 + qA * 8;
    #pragma unroll
    for (int u = 0; u < 14; ++u) *(uint2*)(dA + u * 64) = pk2(vA[u]);
    // B: byte = 960 + ((u<<1)+(pbb>>5))*32 + qB*8
    char* dB = tbb + rowB * (LDSTR * 2) + 960 + (pbb >> 5) * 32 + qB * 8;
    #pragma unroll
    for (int u = 0; u < 2; ++u) *(uint2*)(dB + u * 64) = pk2(vB[u]);
    // C: byte = 1088 + w*16 + qC*8
    if (hasC)
      *(uint2*)(tbb + rowC * (LDSTR * 2) + 1088 + w * 16 + qC * 8) = pk2(vC);
    // D: byte = 1120 + (2*dD + l>>5)*8
    if (hasD)
      *(uint2*)(tbb + rowD * (LDSTR * 2) + 1120 +
                (((dD << 1) + (l >> 5)) << 3)) = pk2(vD);
  }

  // ---------------- phase 0b (late): all 19 B-fragment k-steps from ws --------
  bf16x8 bfw[NKS];
  #pragma unroll
  for (int ks = 0; ks < NKS; ++ks)
    bfw[ks] = *(const bf16x8*)(wsf + ((ks * 4 + w) * 64 + l) * 8);
  __syncthreads();

  // ---------------- phase 2: MFMA over K=608 ----------------------------------
  f32x4 acc[2];
  acc[0] = (f32x4){0.f, 0.f, 0.f, 0.f};
  acc[1] = (f32x4){0.f, 0.f, 0.f, 0.f};
  const unsigned short* arow0 = &fused[(l & 15) * LDSTR + kg];
  const unsigned short* arow1 = arow0 + 16 * LDSTR;
  #pragma unroll
  for (int ks = 0; ks < NKS; ++ks) {
    acc[0] = __builtin_amdgcn_mfma_f32_16x16x32_bf16(
        *(const bf16x8*)(arow0 + (ks << 5)), bfw[ks], acc[0], 0, 0, 0);
    acc[1] = __builtin_amdgcn_mfma_f32_16x16x32_bf16(
        *(const bf16x8*)(arow1 + (ks << 5)), bfw[ks], acc[1], 0, 0, 0);
  }
  __syncthreads();   // all MFMA reads done; safe to alias z1 onto the tile

  // ---------------- phase 2.5: z1 = silu(acc + b1) ----------------------------
  {
    const float b1v = b1[bn];
    const int rb = (l >> 4) << 2;
    #pragma unroll
    for (int mt = 0; mt < 2; ++mt) {
      #pragma unroll
      for (int v = 0; v < 4; ++v) {
        const int row = (mt << 4) + rb + v;      // C/D layout: row=(l>>4)*4+v
        z1[row * Z1STR + bn] = silu_f(acc[mt][v] + b1v);
      }
    }
  }
  __syncthreads();

  // ---------------- phase 3: out = silu(z1 @ W2 + b2) -------------------------
  {
    const int r  = t >> 3;            // 8 threads per row
    const int j0 = (t & 7) << 2;      // 4 output cols each
    float a0 = b2[j0], a1 = b2[j0 + 1], a2 = b2[j0 + 2], a3 = b2[j0 + 3];
    const float4* zr4 = (const float4*)&z1[r * Z1STR];
    #pragma unroll
    for (int k4 = 0; k4 < 16; ++k4) {
      const float4 zv = zr4[k4];
      const float* w2b = W2 + (k4 * 4) * 32 + j0;
      const float4 w0 = *(const float4*)(w2b);
      const float4 w1 = *(const float4*)(w2b + 32);
      const float4 w2v = *(const float4*)(w2b + 64);
      const float4 w3 = *(const float4*)(w2b + 96);
      a0 = __fmaf_rn(zv.x, w0.x, a0); a1 = __fmaf_rn(zv.x, w0.y, a1);
      a2 = __fmaf_rn(zv.x, w0.z, a2); a3 = __fmaf_rn(zv.x, w0.w, a3);
      a0 = __fmaf_rn(zv.y, w1.x, a0); a1 = __fmaf_rn(zv.y, w1.y, a1);
      a2 = __fmaf_rn(zv.y, w1.z, a2); a3 = __fmaf_rn(zv.y, w1.w, a3);
      a0 = __fmaf_rn(zv.z, w2v.x, a0); a1 = __fmaf_rn(zv.z, w2v.y, a1);
      a2 = __fmaf_rn(zv.z, w2v.z, a2); a3 = __fmaf_rn(zv.z, w2v.w, a3);
      a0 = __fmaf_rn(zv.w, w3.x, a0); a1 = __fmaf_rn(zv.w, w3.y, a1);
      a2 = __fmaf_rn(zv.w, w3.z, a2); a3 = __fmaf_rn(zv.w, w3.w, a3);
    }
    float4 o;
    o.x = silu_f(a0); o.y = silu_f(a1); o.z = silu_f(a2); o.w = silu_f(a3);
    *(float4*)(out + (size_t)(R0 + r) * 32 + j0) = o;
  }
}

extern "C" void kernel_launch(void* const* d_in, const int* in_sizes, int n_in,
                              void* d_out, int out_size, void* d_ws, size_t ws_size,
                              hipStream_t stream) {
  const float* xc   = (const float*)d_in[0];
  const int*   xcat = (const int*)  d_in[1];
  const float* emb  = (const float*)d_in[2];
  const float* Wc   = (const float*)d_in[3];
  const float* bc   = (const float*)d_in[4];
  const float* lng  = (const float*)d_in[5];
  const float* lnb  = (const float*)d_in[6];
  const float* W1   = (const float*)d_in[7];
  const float* b1   = (const float*)d_in[8];
  const float* W2   = (const float*)d_in[9];
  const float* b2   = (const float*)d_in[10];
  float* out = (float*)d_out;

  unsigned int* wsf = (unsigned int*)d_ws;     // 77,824 B of W1 fragments
  hipLaunchKernelGGL(prep_w1, dim3((WS_FRAG_DWORDS + 255) / 256), dim3(256),
                     0, stream, W1, wsf);

  const int B = in_sizes[0] / 64;        // 131072
  const int grid = B / BROWS;            // 4096
  hipLaunchKernelGGL(tab_fused, dim3(grid), dim3(256), 0, stream,
                     xc, xcat, emb, Wc, bc, lng, lnb,
                     (const unsigned short*)wsf, b1, W2, b2, out);
}